// Round 1
// baseline (495.394 us; speedup 1.0000x reference)
//
#include <hip/hip_runtime.h>
#include <hip/hip_bf16.h>

using bf16 = __hip_bfloat16;
typedef __attribute__((ext_vector_type(8))) short bf16x8;
typedef __attribute__((ext_vector_type(4))) float f32x4;

#define DEV __device__ __forceinline__

// ---------------------------------------------------------------------------
// constants
static constexpr int Bsz = 8, Nseq = 512, Dm = 768, Vv = 30000, Yv = 30000;
static constexpr int Ypad = 30080;               // padded rows of E_y (mult of 128)
static constexpr int Tok = Bsz * Nseq;           // 4096

// ---------------------------------------------------------------------------
// GEMM: C[M][Nc] = A[M][K] * B[Nc][K]^T   (both operands bf16 row-major, K inner)
// 128x128 tile, BK=32, 4 waves, mfma_f32_16x16x32_bf16, global_load_lds staging.
template<bool STORE_BF16, bool NBOUND, bool SWIZZLE>
__global__ __launch_bounds__(256)
void gemm_bt(const bf16* __restrict__ Ag, const bf16* __restrict__ Bg,
             void* __restrict__ Cg, int M, int Nc, int K, int ldc,
             long sA, long sB, long sC)
{
    __shared__ bf16 As[128 * 32];
    __shared__ bf16 Bs[128 * 32];

    const int bz = blockIdx.z;
    const bf16* A  = Ag + (long)bz * sA;
    const bf16* Bm = Bg + (long)bz * sB;

    int bid = blockIdx.x;
    if (SWIZZLE) {                       // requires gridDim.x % 8 == 0
        int cpx = gridDim.x >> 3;
        bid = (bid & 7) * cpx + (bid >> 3);
    }
    const int nTilesM = M >> 7;
    const int mTile = bid % nTilesM;
    const int nTile = bid / nTilesM;

    const int tid  = threadIdx.x;
    const int wave = tid >> 6;
    const int lane = tid & 63;

    // staging geometry: lane l covers row l/4, col (l%4)*8 within a 16-row stripe
    const int sRow = (wave << 4) + (lane >> 2);
    const int sCol = (lane & 3) << 3;

    const long aBase = (long)(mTile * 128) * K;
    const long bBase = (long)(nTile * 128) * K;

    const int fl = lane & 15;            // fragment row/col
    const int fh = lane >> 4;            // k-subgroup 0..3
    const int wRow = (wave >> 1) << 6;   // 0 / 64
    const int wCol = (wave & 1) << 6;    // 0 / 64

    f32x4 acc[4][4] = {};

    for (int k0 = 0; k0 < K; k0 += 32) {
#pragma unroll
        for (int t = 0; t < 2; ++t) {
            const bf16* gA = A  + aBase + (long)(t * 64 + sRow) * K + (k0 + sCol);
            const bf16* gB = Bm + bBase + (long)(t * 64 + sRow) * K + (k0 + sCol);
            bf16* lA = &As[(t * 64 + (wave << 4)) * 32];
            bf16* lB = &Bs[(t * 64 + (wave << 4)) * 32];
            __builtin_amdgcn_global_load_lds(
                (const __attribute__((address_space(1))) void*)gA,
                (__attribute__((address_space(3))) void*)lA, 16, 0, 0);
            __builtin_amdgcn_global_load_lds(
                (const __attribute__((address_space(1))) void*)gB,
                (__attribute__((address_space(3))) void*)lB, 16, 0, 0);
        }
        __syncthreads();

        bf16x8 af[4], bfg[4];
#pragma unroll
        for (int m = 0; m < 4; ++m)
            af[m] = *(const bf16x8*)&As[(wRow + m * 16 + fl) * 32 + fh * 8];
#pragma unroll
        for (int n = 0; n < 4; ++n)
            bfg[n] = *(const bf16x8*)&Bs[(wCol + n * 16 + fl) * 32 + fh * 8];
#pragma unroll
        for (int m = 0; m < 4; ++m)
#pragma unroll
            for (int n = 0; n < 4; ++n)
                acc[m][n] = __builtin_amdgcn_mfma_f32_16x16x32_bf16(
                    af[m], bfg[n], acc[m][n], 0, 0, 0);
        __syncthreads();
    }

    // epilogue: C layout col = lane&15, row = (lane>>4)*4 + j
    const int rBase = mTile * 128 + wRow + fh * 4;
    const int cBase = nTile * 128 + wCol + fl;
#pragma unroll
    for (int m = 0; m < 4; ++m) {
#pragma unroll
        for (int n = 0; n < 4; ++n) {
            int gc = cBase + n * 16;
            if (NBOUND && gc >= Nc) continue;
            int gr = rBase + m * 16;
            if (STORE_BF16) {
                bf16* C = (bf16*)Cg + (long)bz * sC;
#pragma unroll
                for (int j = 0; j < 4; ++j)
                    C[(long)(gr + j) * ldc + gc] = __float2bfloat16(acc[m][n][j]);
            } else {
                float* C = (float*)Cg + (long)bz * sC;
#pragma unroll
                for (int j = 0; j < 4; ++j)
                    C[(long)(gr + j) * ldc + gc] = acc[m][n][j];
            }
        }
    }
}

// ---------------------------------------------------------------------------
// E_y f32 [30000][768] -> bf16 [30080][768], rows >= 30000 zero-filled
__global__ __launch_bounds__(192) void k_cvt_ey(const float* __restrict__ Ey,
                                                bf16* __restrict__ Eyb)
{
    int row = blockIdx.x;
    int d = threadIdx.x * 4;
    union { bf16 h[4]; uint2 u; } pk;
    if (row < Yv) {
        float4 v = *(const float4*)(Ey + (long)row * Dm + d);
        pk.h[0] = __float2bfloat16(v.x); pk.h[1] = __float2bfloat16(v.y);
        pk.h[2] = __float2bfloat16(v.z); pk.h[3] = __float2bfloat16(v.w);
    } else {
        pk.h[0] = pk.h[1] = pk.h[2] = pk.h[3] = __float2bfloat16(0.f);
    }
    *(uint2*)(Eyb + (long)row * Dm + d) = pk.u;
}

// W f32 [768][768] -> WT bf16 [768][768] with WT[n][k] = W[k][n]
__global__ void k_wT(const float* __restrict__ W, bf16* __restrict__ WT)
{
    __shared__ float t[32][33];
    int bx = blockIdx.x * 32;            // k base
    int by = blockIdx.y * 32;            // n base
    int tx = threadIdx.x, ty = threadIdx.y;
#pragma unroll
    for (int i = 0; i < 32; i += 8)
        t[ty + i][tx] = W[(long)(bx + ty + i) * Dm + (by + tx)];
    __syncthreads();
#pragma unroll
    for (int i = 0; i < 32; i += 8)
        WT[(long)(by + ty + i) * Dm + (bx + tx)] = __float2bfloat16(t[tx][ty + i]);
}

// X = E_v[M_s] -> bf16 [4096][768]
__global__ __launch_bounds__(192) void k_gather(const int* __restrict__ Ms,
                                                const float* __restrict__ Ev,
                                                bf16* __restrict__ Xb)
{
    int token = blockIdx.x;
    int id = Ms[token];
    int d = threadIdx.x * 4;
    float4 v = *(const float4*)(Ev + (long)id * Dm + d);
    union { bf16 h[4]; uint2 u; } pk;
    pk.h[0] = __float2bfloat16(v.x); pk.h[1] = __float2bfloat16(v.y);
    pk.h[2] = __float2bfloat16(v.z); pk.h[3] = __float2bfloat16(v.w);
    *(uint2*)(Xb + (long)token * Dm + d) = pk.u;
}

// XWo bf16 [B][512][768] -> [B][768][512]
__global__ void k_xwoT(const bf16* __restrict__ Xo, bf16* __restrict__ XoT)
{
    __shared__ bf16 t[32][33];
    int b = blockIdx.z;
    const bf16* src = Xo + (long)b * Nseq * Dm;
    bf16* dst = XoT + (long)b * Dm * Nseq;
    int bx = blockIdx.x * 32;            // j base (rows of src)
    int by = blockIdx.y * 32;            // d base (cols of src)
    int tx = threadIdx.x, ty = threadIdx.y;
#pragma unroll
    for (int i = 0; i < 32; i += 8)
        t[ty + i][tx] = src[(long)(bx + ty + i) * Dm + (by + tx)];
    __syncthreads();
#pragma unroll
    for (int i = 0; i < 32; i += 8)
        dst[(long)(by + ty + i) * Nseq + (bx + tx)] = t[tx][ty + i];
}

// ---------------------------------------------------------------------------
DEV float waveMax(float v) {
#pragma unroll
    for (int o = 32; o > 0; o >>= 1) v = fmaxf(v, __shfl_xor(v, o, 64));
    return v;
}
DEV float waveSum(float v) {
#pragma unroll
    for (int o = 32; o > 0; o >>= 1) v += __shfl_xor(v, o, 64);
    return v;
}

// softmax over j of (L[b,i,j] + (j-i)) with mask; writes A f32 (d_out) + bf16
__global__ __launch_bounds__(256) void k_softmax(const float* __restrict__ L,
                                                 const int* __restrict__ Ms,
                                                 float* __restrict__ Aout,
                                                 bf16* __restrict__ Ab)
{
    __shared__ float red[8];
    int row = blockIdx.x;                // 0..4095 == b*512+i
    int b = row >> 9, i = row & 511;
    const float* l = L + (long)row * Nseq;
    const int* ms = Ms + (b << 9);
    int t = threadIdx.x;
    int wid = t >> 6, lane = t & 63;
    int j0 = t, j1 = t + 256;

    float a0 = l[j0] + (float)(j0 - i);
    float a1 = l[j1] + (float)(j1 - i);
    if (ms[j0] == 0) a0 = -1e12f;
    if (ms[j1] == 0) a1 = -1e12f;

    float m = waveMax(fmaxf(a0, a1));
    if (lane == 0) red[wid] = m;
    __syncthreads();
    m = fmaxf(fmaxf(red[0], red[1]), fmaxf(red[2], red[3]));

    float e0 = expf(a0 - m), e1 = expf(a1 - m);
    float s = waveSum(e0 + e1);
    if (lane == 0) red[4 + wid] = s;
    __syncthreads();
    s = red[4] + red[5] + red[6] + red[7];
    float inv = 1.0f / s;

    float r0 = e0 * inv, r1 = e1 * inv;
    Aout[(long)row * Nseq + j0] = r0;
    Aout[(long)row * Nseq + j1] = r1;
    Ab[(long)row * Nseq + j0] = __float2bfloat16(r0);
    Ab[(long)row * Nseq + j1] = __float2bfloat16(r1);
}

// H = LN(Qc + E_v[Ms]) * gamma + beta  -> bf16
__global__ __launch_bounds__(256) void k_ln(const float* __restrict__ Qc,
                                            const int* __restrict__ Ms,
                                            const float* __restrict__ Ev,
                                            const float* __restrict__ gamma,
                                            const float* __restrict__ beta,
                                            bf16* __restrict__ Hb)
{
    __shared__ float red[8];
    int row = blockIdx.x;
    int id = Ms[row];
    const float* q = Qc + (long)row * Dm;
    const float* e = Ev + (long)id * Dm;
    int t = threadIdx.x;
    int wid = t >> 6, lane = t & 63;

    float x[3];
#pragma unroll
    for (int c = 0; c < 3; ++c) x[c] = q[t + c * 256] + e[t + c * 256];

    float s = waveSum(x[0] + x[1] + x[2]);
    if (lane == 0) red[wid] = s;
    __syncthreads();
    float mu = (red[0] + red[1] + red[2] + red[3]) * (1.0f / 768.0f);

    float vs = 0.f;
#pragma unroll
    for (int c = 0; c < 3; ++c) { float d = x[c] - mu; vs += d * d; }
    vs = waveSum(vs);
    if (lane == 0) red[4 + wid] = vs;
    __syncthreads();
    float var = (red[4] + red[5] + red[6] + red[7]) * (1.0f / 768.0f);
    float rstd = rsqrtf(var + 1e-5f);

#pragma unroll
    for (int c = 0; c < 3; ++c) {
        int d = t + c * 256;
        Hb[(long)row * Dm + d] =
            __float2bfloat16((x[c] - mu) * rstd * gamma[d] + beta[d]);
    }
}

// ---------------------------------------------------------------------------
extern "C" void kernel_launch(void* const* d_in, const int* in_sizes, int n_in,
                              void* d_out, int out_size, void* d_ws, size_t ws_size,
                              hipStream_t stream)
{
    const int*   Ms    = (const int*)d_in[0];
    const float* Ev    = (const float*)d_in[1];
    const float* Ey    = (const float*)d_in[2];
    const float* WA    = (const float*)d_in[3];
    const float* WO    = (const float*)d_in[4];
    const float* gamma = (const float*)d_in[5];
    const float* beta  = (const float*)d_in[6];

    float* y_out = (float*)d_out;                       // [4096][30000]
    float* A_out = y_out + (size_t)Tok * Yv;            // [8][512][512]

    char* ws = (char*)d_ws;
    size_t off = 0;
    auto alloc = [&](size_t n) { char* p = ws + off; off += (n + 255) & ~(size_t)255; return p; };
    bf16*  Xb    = (bf16*) alloc((size_t)Tok * Dm * 2);
    bf16*  WAbT  = (bf16*) alloc((size_t)Dm * Dm * 2);
    bf16*  WObT  = (bf16*) alloc((size_t)Dm * Dm * 2);
    bf16*  QWb   = (bf16*) alloc((size_t)Tok * Dm * 2);
    bf16*  XWob  = (bf16*) alloc((size_t)Tok * Dm * 2);
    bf16*  XWobT = (bf16*) alloc((size_t)Tok * Dm * 2);
    float* Lf    = (float*)alloc((size_t)Tok * Nseq * 4);
    bf16*  Ab    = (bf16*) alloc((size_t)Tok * Nseq * 2);
    float* Qc    = (float*)alloc((size_t)Tok * Dm * 4);
    bf16*  Hb    = (bf16*) alloc((size_t)Tok * Dm * 2);
    bf16*  Eyb   = (bf16*) alloc((size_t)Ypad * Dm * 2);

    // 1. convert + pad E_y
    k_cvt_ey<<<dim3(Ypad), dim3(192), 0, stream>>>(Ey, Eyb);
    // 2. transpose-convert W_A, W_O
    k_wT<<<dim3(24, 24), dim3(32, 8), 0, stream>>>(WA, WAbT);
    k_wT<<<dim3(24, 24), dim3(32, 8), 0, stream>>>(WO, WObT);
    // 3. gather embeddings
    k_gather<<<dim3(Tok), dim3(192), 0, stream>>>(Ms, Ev, Xb);
    // 4. QW = X @ W_A  (bf16 out)
    gemm_bt<true, false, false><<<dim3(192), dim3(256), 0, stream>>>(
        Xb, WAbT, (void*)QWb, Tok, Dm, Dm, Dm, 0L, 0L, 0L);
    // 5. XWo = X @ W_O (bf16 out)
    gemm_bt<true, false, false><<<dim3(192), dim3(256), 0, stream>>>(
        Xb, WObT, (void*)XWob, Tok, Dm, Dm, Dm, 0L, 0L, 0L);
    // 6. logits = QW @ X^T per batch (f32 out)
    gemm_bt<false, false, false><<<dim3(16, 1, 8), dim3(256), 0, stream>>>(
        QWb, Xb, (void*)Lf, Nseq, Nseq, Dm, Nseq,
        (long)Nseq * Dm, (long)Nseq * Dm, (long)Nseq * Nseq);
    // 7. bias + mask + softmax -> A (f32 in d_out) and Ab (bf16)
    k_softmax<<<dim3(Tok), dim3(256), 0, stream>>>(Lf, Ms, A_out, Ab);
    // 8. transpose XWo per batch
    k_xwoT<<<dim3(16, 24, 8), dim3(32, 8), 0, stream>>>(XWob, XWobT);
    // 9. Qc = A @ XWo per batch (f32 out)
    gemm_bt<false, false, false><<<dim3(24, 1, 8), dim3(256), 0, stream>>>(
        Ab, XWobT, (void*)Qc, Nseq, Dm, Nseq, Dm,
        (long)Nseq * Nseq, (long)Dm * Nseq, (long)Nseq * Dm);
    // 10. H = LN(Qc + X)
    k_ln<<<dim3(Tok), dim3(256), 0, stream>>>(Qc, Ms, Ev, gamma, beta, Hb);
    // 11. y_logits = H @ E_y^T  (f32 to d_out, col-bounded, XCD swizzle)
    gemm_bt<false, true, true><<<dim3(32 * (Ypad / 128)), dim3(256), 0, stream>>>(
        Hb, Eyb, d_out, Tok, Yv, Dm, Yv, 0L, 0L, 0L);
}

// Round 2
// 427.892 us; speedup vs baseline: 1.1578x; 1.1578x over previous
//
#include <hip/hip_runtime.h>
#include <hip/hip_bf16.h>

using bf16 = __hip_bfloat16;
typedef __attribute__((ext_vector_type(8))) short bf16x8;
typedef __attribute__((ext_vector_type(4))) float f32x4;

#define DEV __device__ __forceinline__

// ---------------------------------------------------------------------------
// constants
static constexpr int Bsz = 8, Nseq = 512, Dm = 768, Vv = 30000, Yv = 30000;
static constexpr int Ypad = 30208;               // 118 tiles of 256
static constexpr int Tok = Bsz * Nseq;           // 4096
static constexpr int NT = Dm / 64;               // 12 K-tiles of 64

// ---------------------------------------------------------------------------
// Big GEMM: C[M][Yv] (f32) = A[M][768]_bf16 * B[Ypad][768]_bf16^T
// 256x256 tile, BK=64, 8 waves, double-buffered LDS, counted vmcnt pipeline,
// XOR-swizzled LDS (slot ^= row&7), setprio MFMA clusters, XCD swizzle.
__global__ __launch_bounds__(512, 2)
void gemm_big(const bf16* __restrict__ Ag, const bf16* __restrict__ Bg,
              float* __restrict__ Cg)
{
    __shared__ bf16 lds[2][2][256 * 64];         // [buf][A/B][tile] = 128 KiB

    // XCD-aware bijective swizzle (gridDim.x = 1888, % 8 == 0)
    int bid = blockIdx.x;
    {
        int cpx = gridDim.x >> 3;
        bid = (bid & 7) * cpx + (bid >> 3);
    }
    const int mTile = bid & 15;                  // 16 M-tiles (consecutive bids share B-panel)
    const int nTile = bid >> 4;                  // 118 N-tiles

    const int tid  = threadIdx.x;
    const int lane = tid & 63;
    const int wid  = tid >> 6;
    const int wm   = wid >> 2;                   // 0..1 -> 128-row half
    const int wn   = wid & 3;                    // 0..3 -> 64-col slice

    // ---- staging geometry (global_load_lds, wave-uniform LDS base + lane*16)
    // LDS chunk c = j*512 + tid : row = c/8, slot = c&7 (8 x 16B slots per 64-elem row)
    // swizzle: LDS(row, slot) holds source col-chunk slot ^ (row&7)
    const int swzCol = ((tid & 7) ^ ((tid >> 3) & 7)) << 3;
    const bf16* aSrc = Ag + (long)(mTile * 256 + (tid >> 3)) * Dm + swzCol;
    const bf16* bSrc = Bg + (long)(nTile * 256 + (tid >> 3)) * Dm + swzCol;
    const int ldsW = (wid << 9);                 // wave-uniform element base (j adds 4096)

    // ---- fragment read geometry
    const int fl = lane & 15;
    const int fh = lane >> 4;
    const int sw0 = fh ^ (fl & 7);               // ks=0 slot
    const int sw1 = sw0 ^ 4;                     // ks=1 slot
    const int aB0 = (wm * 128 + fl) * 64 + sw0 * 8;
    const int aB1 = (wm * 128 + fl) * 64 + sw1 * 8;
    const int bB0 = (wn * 64 + fl) * 64 + sw0 * 8;
    const int bB1 = (wn * 64 + fl) * 64 + sw1 * 8;

    f32x4 acc[8][4] = {};

    // ---- prologue: stage tiles 0 and 1 (16 loads in flight)
#pragma unroll
    for (int T = 0; T < 2; ++T) {
#pragma unroll
        for (int j = 0; j < 4; ++j) {
            __builtin_amdgcn_global_load_lds(
                (const __attribute__((address_space(1))) void*)(aSrc + (long)j * 64 * Dm + T * 64),
                (__attribute__((address_space(3))) void*)&lds[T][0][j * 4096 + ldsW], 16, 0, 0);
            __builtin_amdgcn_global_load_lds(
                (const __attribute__((address_space(1))) void*)(bSrc + (long)j * 64 * Dm + T * 64),
                (__attribute__((address_space(3))) void*)&lds[T][1][j * 4096 + ldsW], 16, 0, 0);
        }
    }

#pragma unroll
    for (int t = 0; t < NT; ++t) {
        // confirm tile t landed (issued 2 tiles ago); keep next tile's loads in flight
        if (t < NT - 1) asm volatile("s_waitcnt vmcnt(8)" ::: "memory");
        else            asm volatile("s_waitcnt vmcnt(0)" ::: "memory");
        __builtin_amdgcn_sched_barrier(0);
        __builtin_amdgcn_s_barrier();
        __builtin_amdgcn_sched_barrier(0);

        const int b = t & 1;
        const bf16* Asl = lds[b][0];
        const bf16* Bsl = lds[b][1];

        bf16x8 bfr[4][2];
#pragma unroll
        for (int n = 0; n < 4; ++n) {
            bfr[n][0] = *(const bf16x8*)&Bsl[bB0 + n * 1024];
            bfr[n][1] = *(const bf16x8*)&Bsl[bB1 + n * 1024];
        }
#pragma unroll
        for (int mh = 0; mh < 2; ++mh) {
            bf16x8 am[4][2];
#pragma unroll
            for (int mm = 0; mm < 4; ++mm) {
                am[mm][0] = *(const bf16x8*)&Asl[aB0 + mh * 4096 + mm * 1024];
                am[mm][1] = *(const bf16x8*)&Asl[aB1 + mh * 4096 + mm * 1024];
            }
            __builtin_amdgcn_s_setprio(1);
#pragma unroll
            for (int mm = 0; mm < 4; ++mm)
#pragma unroll
                for (int n = 0; n < 4; ++n) {
                    acc[mh * 4 + mm][n] = __builtin_amdgcn_mfma_f32_16x16x32_bf16(
                        am[mm][0], bfr[n][0], acc[mh * 4 + mm][n], 0, 0, 0);
                    acc[mh * 4 + mm][n] = __builtin_amdgcn_mfma_f32_16x16x32_bf16(
                        am[mm][1], bfr[n][1], acc[mh * 4 + mm][n], 0, 0, 0);
                }
            __builtin_amdgcn_s_setprio(0);
        }

        // all waves done reading buf[t&1] -> safe to stage tile t+2 into it
        __builtin_amdgcn_sched_barrier(0);
        __builtin_amdgcn_s_barrier();
        __builtin_amdgcn_sched_barrier(0);

        if (t < NT - 2) {
            const int sb = t & 1;                // (t+2) & 1
            const long kof = (long)(t + 2) * 64;
#pragma unroll
            for (int j = 0; j < 4; ++j) {
                __builtin_amdgcn_global_load_lds(
                    (const __attribute__((address_space(1))) void*)(aSrc + (long)j * 64 * Dm + kof),
                    (__attribute__((address_space(3))) void*)&lds[sb][0][j * 4096 + ldsW], 16, 0, 0);
                __builtin_amdgcn_global_load_lds(
                    (const __attribute__((address_space(1))) void*)(bSrc + (long)j * 64 * Dm + kof),
                    (__attribute__((address_space(3))) void*)&lds[sb][1][j * 4096 + ldsW], 16, 0, 0);
            }
        }
    }

    // ---- epilogue: f32 store, col = lane&15, row = (lane>>4)*4 + j
    const int row0 = mTile * 256 + wm * 128;
    const int col0 = nTile * 256 + wn * 64;
#pragma unroll
    for (int mh = 0; mh < 2; ++mh)
#pragma unroll
        for (int mm = 0; mm < 4; ++mm)
#pragma unroll
            for (int n = 0; n < 4; ++n) {
                const int c = col0 + n * 16 + fl;
                if (c >= Yv) continue;
                const int r = row0 + mh * 64 + mm * 16 + fh * 4;
#pragma unroll
                for (int j = 0; j < 4; ++j)
                    Cg[(long)(r + j) * Yv + c] = acc[mh * 4 + mm][n][j];
            }
}

// ---------------------------------------------------------------------------
// GEMM: C[M][Nc] = A[M][K] * B[Nc][K]^T   (m97-structure, for the small GEMMs)
template<bool STORE_BF16>
__global__ __launch_bounds__(256)
void gemm_bt(const bf16* __restrict__ Ag, const bf16* __restrict__ Bg,
             void* __restrict__ Cg, int M, int Nc, int K, int ldc,
             long sA, long sB, long sC)
{
    __shared__ bf16 As[128 * 32];
    __shared__ bf16 Bs[128 * 32];

    const int bz = blockIdx.z;
    const bf16* A  = Ag + (long)bz * sA;
    const bf16* Bm = Bg + (long)bz * sB;

    const int bid = blockIdx.x;
    const int nTilesM = M >> 7;
    const int mTile = bid % nTilesM;
    const int nTile = bid / nTilesM;

    const int tid  = threadIdx.x;
    const int wave = tid >> 6;
    const int lane = tid & 63;

    const int sRow = (wave << 4) + (lane >> 2);
    const int sCol = (lane & 3) << 3;

    const long aBase = (long)(mTile * 128) * K;
    const long bBase = (long)(nTile * 128) * K;

    const int fl = lane & 15;
    const int fh = lane >> 4;
    const int wRow = (wave >> 1) << 6;
    const int wCol = (wave & 1) << 6;

    f32x4 acc[4][4] = {};

    for (int k0 = 0; k0 < K; k0 += 32) {
#pragma unroll
        for (int t = 0; t < 2; ++t) {
            const bf16* gA = A  + aBase + (long)(t * 64 + sRow) * K + (k0 + sCol);
            const bf16* gB = Bm + bBase + (long)(t * 64 + sRow) * K + (k0 + sCol);
            bf16* lA = &As[(t * 64 + (wave << 4)) * 32];
            bf16* lB = &Bs[(t * 64 + (wave << 4)) * 32];
            __builtin_amdgcn_global_load_lds(
                (const __attribute__((address_space(1))) void*)gA,
                (__attribute__((address_space(3))) void*)lA, 16, 0, 0);
            __builtin_amdgcn_global_load_lds(
                (const __attribute__((address_space(1))) void*)gB,
                (__attribute__((address_space(3))) void*)lB, 16, 0, 0);
        }
        __syncthreads();

        bf16x8 af[4], bfg[4];
#pragma unroll
        for (int m = 0; m < 4; ++m)
            af[m] = *(const bf16x8*)&As[(wRow + m * 16 + fl) * 32 + fh * 8];
#pragma unroll
        for (int n = 0; n < 4; ++n)
            bfg[n] = *(const bf16x8*)&Bs[(wCol + n * 16 + fl) * 32 + fh * 8];
#pragma unroll
        for (int m = 0; m < 4; ++m)
#pragma unroll
            for (int n = 0; n < 4; ++n)
                acc[m][n] = __builtin_amdgcn_mfma_f32_16x16x32_bf16(
                    af[m], bfg[n], acc[m][n], 0, 0, 0);
        __syncthreads();
    }

    const int rBase = mTile * 128 + wRow + fh * 4;
    const int cBase = nTile * 128 + wCol + fl;
#pragma unroll
    for (int m = 0; m < 4; ++m) {
#pragma unroll
        for (int n = 0; n < 4; ++n) {
            int gc = cBase + n * 16;
            int gr = rBase + m * 16;
            if (STORE_BF16) {
                bf16* C = (bf16*)Cg + (long)bz * sC;
#pragma unroll
                for (int j = 0; j < 4; ++j)
                    C[(long)(gr + j) * ldc + gc] = __float2bfloat16(acc[m][n][j]);
            } else {
                float* C = (float*)Cg + (long)bz * sC;
#pragma unroll
                for (int j = 0; j < 4; ++j)
                    C[(long)(gr + j) * ldc + gc] = acc[m][n][j];
            }
        }
    }
}

// ---------------------------------------------------------------------------
// E_y f32 [30000][768] -> bf16 [30208][768], rows >= 30000 zero-filled
__global__ __launch_bounds__(192) void k_cvt_ey(const float* __restrict__ Ey,
                                                bf16* __restrict__ Eyb)
{
    int row = blockIdx.x;
    int d = threadIdx.x * 4;
    union { bf16 h[4]; uint2 u; } pk;
    if (row < Yv) {
        float4 v = *(const float4*)(Ey + (long)row * Dm + d);
        pk.h[0] = __float2bfloat16(v.x); pk.h[1] = __float2bfloat16(v.y);
        pk.h[2] = __float2bfloat16(v.z); pk.h[3] = __float2bfloat16(v.w);
    } else {
        pk.h[0] = pk.h[1] = pk.h[2] = pk.h[3] = __float2bfloat16(0.f);
    }
    *(uint2*)(Eyb + (long)row * Dm + d) = pk.u;
}

// W f32 [768][768] -> WT bf16 with WT[n][k] = W[k][n]; z selects (W_A, W_O)
__global__ void k_wT(const float* __restrict__ WA, const float* __restrict__ WO,
                     bf16* __restrict__ WAT, bf16* __restrict__ WOT)
{
    __shared__ float t[32][33];
    const float* W = blockIdx.z ? WO : WA;
    bf16* WT = blockIdx.z ? WOT : WAT;
    int bx = blockIdx.x * 32;
    int by = blockIdx.y * 32;
    int tx = threadIdx.x, ty = threadIdx.y;
#pragma unroll
    for (int i = 0; i < 32; i += 8)
        t[ty + i][tx] = W[(long)(bx + ty + i) * Dm + (by + tx)];
    __syncthreads();
#pragma unroll
    for (int i = 0; i < 32; i += 8)
        WT[(long)(by + ty + i) * Dm + (bx + tx)] = __float2bfloat16(t[tx][ty + i]);
}

// X = E_v[M_s] -> bf16 [4096][768]
__global__ __launch_bounds__(192) void k_gather(const int* __restrict__ Ms,
                                                const float* __restrict__ Ev,
                                                bf16* __restrict__ Xb)
{
    int token = blockIdx.x;
    int id = Ms[token];
    int d = threadIdx.x * 4;
    float4 v = *(const float4*)(Ev + (long)id * Dm + d);
    union { bf16 h[4]; uint2 u; } pk;
    pk.h[0] = __float2bfloat16(v.x); pk.h[1] = __float2bfloat16(v.y);
    pk.h[2] = __float2bfloat16(v.z); pk.h[3] = __float2bfloat16(v.w);
    *(uint2*)(Xb + (long)token * Dm + d) = pk.u;
}

// XWo bf16 [B][512][768] -> [B][768][512]
__global__ void k_xwoT(const bf16* __restrict__ Xo, bf16* __restrict__ XoT)
{
    __shared__ bf16 t[32][33];
    int b = blockIdx.z;
    const bf16* src = Xo + (long)b * Nseq * Dm;
    bf16* dst = XoT + (long)b * Dm * Nseq;
    int bx = blockIdx.x * 32;
    int by = blockIdx.y * 32;
    int tx = threadIdx.x, ty = threadIdx.y;
#pragma unroll
    for (int i = 0; i < 32; i += 8)
        t[ty + i][tx] = src[(long)(bx + ty + i) * Dm + (by + tx)];
    __syncthreads();
#pragma unroll
    for (int i = 0; i < 32; i += 8)
        dst[(long)(by + ty + i) * Nseq + (bx + tx)] = t[tx][ty + i];
}

// ---------------------------------------------------------------------------
DEV float waveMax(float v) {
#pragma unroll
    for (int o = 32; o > 0; o >>= 1) v = fmaxf(v, __shfl_xor(v, o, 64));
    return v;
}
DEV float waveSum(float v) {
#pragma unroll
    for (int o = 32; o > 0; o >>= 1) v += __shfl_xor(v, o, 64);
    return v;
}

// softmax over j of (L[b,i,j] + (j-i)) with mask; writes A f32 (d_out) + bf16
__global__ __launch_bounds__(256) void k_softmax(const float* __restrict__ L,
                                                 const int* __restrict__ Ms,
                                                 float* __restrict__ Aout,
                                                 bf16* __restrict__ Ab)
{
    __shared__ float red[8];
    int row = blockIdx.x;
    int b = row >> 9, i = row & 511;
    const float* l = L + (long)row * Nseq;
    const int* ms = Ms + (b << 9);
    int t = threadIdx.x;
    int wid = t >> 6, lane = t & 63;
    int j0 = t, j1 = t + 256;

    float a0 = l[j0] + (float)(j0 - i);
    float a1 = l[j1] + (float)(j1 - i);
    if (ms[j0] == 0) a0 = -1e12f;
    if (ms[j1] == 0) a1 = -1e12f;

    float m = waveMax(fmaxf(a0, a1));
    if (lane == 0) red[wid] = m;
    __syncthreads();
    m = fmaxf(fmaxf(red[0], red[1]), fmaxf(red[2], red[3]));

    float e0 = expf(a0 - m), e1 = expf(a1 - m);
    float s = waveSum(e0 + e1);
    if (lane == 0) red[4 + wid] = s;
    __syncthreads();
    s = red[4] + red[5] + red[6] + red[7];
    float inv = 1.0f / s;

    float r0 = e0 * inv, r1 = e1 * inv;
    Aout[(long)row * Nseq + j0] = r0;
    Aout[(long)row * Nseq + j1] = r1;
    Ab[(long)row * Nseq + j0] = __float2bfloat16(r0);
    Ab[(long)row * Nseq + j1] = __float2bfloat16(r1);
}

// H = LN(Qc + E_v[Ms]) * gamma + beta  -> bf16
__global__ __launch_bounds__(256) void k_ln(const float* __restrict__ Qc,
                                            const int* __restrict__ Ms,
                                            const float* __restrict__ Ev,
                                            const float* __restrict__ gamma,
                                            const float* __restrict__ beta,
                                            bf16* __restrict__ Hb)
{
    __shared__ float red[8];
    int row = blockIdx.x;
    int id = Ms[row];
    const float* q = Qc + (long)row * Dm;
    const float* e = Ev + (long)id * Dm;
    int t = threadIdx.x;
    int wid = t >> 6, lane = t & 63;

    float x[3];
#pragma unroll
    for (int c = 0; c < 3; ++c) x[c] = q[t + c * 256] + e[t + c * 256];

    float s = waveSum(x[0] + x[1] + x[2]);
    if (lane == 0) red[wid] = s;
    __syncthreads();
    float mu = (red[0] + red[1] + red[2] + red[3]) * (1.0f / 768.0f);

    float vs = 0.f;
#pragma unroll
    for (int c = 0; c < 3; ++c) { float d = x[c] - mu; vs += d * d; }
    vs = waveSum(vs);
    if (lane == 0) red[4 + wid] = vs;
    __syncthreads();
    float var = (red[4] + red[5] + red[6] + red[7]) * (1.0f / 768.0f);
    float rstd = rsqrtf(var + 1e-5f);

#pragma unroll
    for (int c = 0; c < 3; ++c) {
        int d = t + c * 256;
        Hb[(long)row * Dm + d] =
            __float2bfloat16((x[c] - mu) * rstd * gamma[d] + beta[d]);
    }
}

// ---------------------------------------------------------------------------
extern "C" void kernel_launch(void* const* d_in, const int* in_sizes, int n_in,
                              void* d_out, int out_size, void* d_ws, size_t ws_size,
                              hipStream_t stream)
{
    const int*   Ms    = (const int*)d_in[0];
    const float* Ev    = (const float*)d_in[1];
    const float* Ey    = (const float*)d_in[2];
    const float* WA    = (const float*)d_in[3];
    const float* WO    = (const float*)d_in[4];
    const float* gamma = (const float*)d_in[5];
    const float* beta  = (const float*)d_in[6];

    float* y_out = (float*)d_out;                       // [4096][30000]
    float* A_out = y_out + (size_t)Tok * Yv;            // [8][512][512]

    char* ws = (char*)d_ws;
    size_t off = 0;
    auto alloc = [&](size_t n) { char* p = ws + off; off += (n + 255) & ~(size_t)255; return p; };
    bf16*  Xb    = (bf16*) alloc((size_t)Tok * Dm * 2);
    bf16*  WAbT  = (bf16*) alloc((size_t)Dm * Dm * 2);
    bf16*  WObT  = (bf16*) alloc((size_t)Dm * Dm * 2);
    bf16*  QWb   = (bf16*) alloc((size_t)Tok * Dm * 2);
    bf16*  XWob  = (bf16*) alloc((size_t)Tok * Dm * 2);
    bf16*  XWobT = (bf16*) alloc((size_t)Tok * Dm * 2);
    float* Lf    = (float*)alloc((size_t)Tok * Nseq * 4);
    bf16*  Ab    = (bf16*) alloc((size_t)Tok * Nseq * 2);
    float* Qc    = (float*)alloc((size_t)Tok * Dm * 4);
    bf16*  Hb    = (bf16*) alloc((size_t)Tok * Dm * 2);
    bf16*  Eyb   = (bf16*) alloc((size_t)Ypad * Dm * 2);

    // 1. convert + pad E_y
    k_cvt_ey<<<dim3(Ypad), dim3(192), 0, stream>>>(Ey, Eyb);
    // 2. transpose-convert W_A and W_O (one launch)
    k_wT<<<dim3(24, 24, 2), dim3(32, 8), 0, stream>>>(WA, WO, WAbT, WObT);
    // 3. gather embeddings
    k_gather<<<dim3(Tok), dim3(192), 0, stream>>>(Ms, Ev, Xb);
    // 4. QW = X @ W_A  (bf16 out)
    gemm_bt<true><<<dim3(192), dim3(256), 0, stream>>>(
        Xb, WAbT, (void*)QWb, Tok, Dm, Dm, Dm, 0L, 0L, 0L);
    // 5. XWo = X @ W_O (bf16 out)
    gemm_bt<true><<<dim3(192), dim3(256), 0, stream>>>(
        Xb, WObT, (void*)XWob, Tok, Dm, Dm, Dm, 0L, 0L, 0L);
    // 6. logits = QW @ X^T per batch (f32 out)
    gemm_bt<false><<<dim3(16, 1, 8), dim3(256), 0, stream>>>(
        QWb, Xb, (void*)Lf, Nseq, Nseq, Dm, Nseq,
        (long)Nseq * Dm, (long)Nseq * Dm, (long)Nseq * Nseq);
    // 7. bias + mask + softmax -> A (f32 in d_out) and Ab (bf16)
    k_softmax<<<dim3(Tok), dim3(256), 0, stream>>>(Lf, Ms, A_out, Ab);
    // 8. transpose XWo per batch
    k_xwoT<<<dim3(16, 24, 8), dim3(32, 8), 0, stream>>>(XWob, XWobT);
    // 9. Qc = A @ XWo per batch (f32 out)
    gemm_bt<false><<<dim3(24, 1, 8), dim3(256), 0, stream>>>(
        Ab, XWobT, (void*)Qc, Nseq, Dm, Nseq, Dm,
        (long)Nseq * Nseq, (long)Dm * Nseq, (long)Nseq * Dm);
    // 10. H = LN(Qc + X)
    k_ln<<<dim3(Tok), dim3(256), 0, stream>>>(Qc, Ms, Ev, gamma, beta, Hb);
    // 11. y_logits = H @ E_y^T  (f32, 256^2 pipelined kernel)
    gemm_big<<<dim3(16 * (Ypad / 256)), dim3(512), 0, stream>>>(Hb, Eyb, y_out);
}

// Round 3
// 391.369 us; speedup vs baseline: 1.2658x; 1.0933x over previous
//
#include <hip/hip_runtime.h>
#include <hip/hip_bf16.h>

using bf16 = __hip_bfloat16;
typedef __attribute__((ext_vector_type(8))) short bf16x8;
typedef __attribute__((ext_vector_type(4))) float f32x4;

#define DEV __device__ __forceinline__

#define AS1 __attribute__((address_space(1)))
#define AS3 __attribute__((address_space(3)))
#define SB  __builtin_amdgcn_sched_barrier(0)
#define BARR __builtin_amdgcn_s_barrier()
#define LG0 asm volatile("s_waitcnt lgkmcnt(0)" ::: "memory")
#define VM4 asm volatile("s_waitcnt vmcnt(4)" ::: "memory")
#define VM0 asm volatile("s_waitcnt vmcnt(0)" ::: "memory")

// ---------------------------------------------------------------------------
// constants
static constexpr int Bsz = 8, Nseq = 512, Dm = 768, Vv = 30000, Yv = 30000;
static constexpr int Ypad = 30208;               // 118 tiles of 256
static constexpr int Tok = Bsz * Nseq;           // 4096
static constexpr int NT = Dm / 64;               // 12 K-tiles of 64

// 16-MFMA cluster for quadrant (MQ,NQ), setprio-wrapped (T5)
#define MF16(MQ, NQ)                                                          \
    __builtin_amdgcn_s_setprio(1);                                            \
    _Pragma("unroll") for (int mm = 0; mm < 4; ++mm)                          \
    _Pragma("unroll") for (int nn = 0; nn < 2; ++nn) {                        \
        acc[(MQ)*4+mm][(NQ)*2+nn] = __builtin_amdgcn_mfma_f32_16x16x32_bf16(  \
            afr[mm][0], bfr[nn][0], acc[(MQ)*4+mm][(NQ)*2+nn], 0, 0, 0);      \
        acc[(MQ)*4+mm][(NQ)*2+nn] = __builtin_amdgcn_mfma_f32_16x16x32_bf16(  \
            afr[mm][1], bfr[nn][1], acc[(MQ)*4+mm][(NQ)*2+nn], 0, 0, 0);      \
    }                                                                         \
    __builtin_amdgcn_s_setprio(0);

// ---------------------------------------------------------------------------
// Big GEMM: C[4096][Yv] f32 = A[4096][768]_bf16 * B[Ypad][768]_bf16^T
// 256x256 tile, BK=64, 8 waves, 8-phase schedule (m201 port), 128 KiB LDS.
// Chunks: ci = slot*4 + op*2 + h  (op: A=0,B=1; h: 128-row half; slot: K-tile parity)
__global__ __launch_bounds__(512, 2)
void gemm_big(const bf16* __restrict__ Ag, const bf16* __restrict__ Bg,
              float* __restrict__ Cg)
{
    __shared__ bf16 sm[8][8192];                 // 8 x 16 KiB = 128 KiB

    int bid = blockIdx.x;
    { int cpx = gridDim.x >> 3; bid = (bid & 7) * cpx + (bid >> 3); }
    const int mTile = bid & 15;
    const int nTile = bid >> 4;

    const int tid  = threadIdx.x;
    const int lane = tid & 63;
    const int wid  = tid >> 6;
    const int wm   = wid >> 2;                   // 0..1
    const int wn   = wid & 3;                    // 0..3

    // staging: thread covers LDS 16B-chunk (l*512+tid); row=c/8, slot8=c&7.
    // swizzle: LDS slot s of row r holds source col-chunk s^(r&7)
    const int lr = tid >> 3;
    const int sc = ((tid & 7) ^ (lr & 7)) << 3;
    const bf16* aS = Ag + (long)(mTile * 256 + lr) * Dm + sc;
    const bf16* bS = Bg + (long)(nTile * 256 + lr) * Dm + sc;
    const int ldsOff = wid << 9;                 // + l*4096, lane*8 implicit

    auto stage = [&](int ci, int op, int h, int tile) {
        const bf16* s = (op ? bS : aS) + (long)h * 128 * Dm + tile * 64;
        __builtin_amdgcn_global_load_lds((const AS1 void*)s,
            (AS3 void*)&sm[ci][ldsOff], 16, 0, 0);
        __builtin_amdgcn_global_load_lds((const AS1 void*)(s + (long)64 * Dm),
            (AS3 void*)&sm[ci][4096 + ldsOff], 16, 0, 0);
    };

    // frag read geometry: row*64 + ((ks*4+fh)^(row&7))*8 ; row&7 == fl&7
    const int fl = lane & 15;
    const int fh = lane >> 4;
    const int e0 = (fh ^ (fl & 7)) << 3;
    const int aro = (wm * 64 + fl) * 64;
    const int bro = (wn * 32 + fl) * 64;

    f32x4 acc[8][4] = {};
    bf16x8 afr[4][2], bfr[2][2];

    auto rdA = [&](int ci) {
#pragma unroll
        for (int mm = 0; mm < 4; ++mm) {
            afr[mm][0] = *(const bf16x8*)&sm[ci][aro + mm * 1024 + e0];
            afr[mm][1] = *(const bf16x8*)&sm[ci][aro + mm * 1024 + (e0 ^ 32)];
        }
    };
    auto rdB = [&](int ci) {
#pragma unroll
        for (int nn = 0; nn < 2; ++nn) {
            bfr[nn][0] = *(const bf16x8*)&sm[ci][bro + nn * 1024 + e0];
            bfr[nn][1] = *(const bf16x8*)&sm[ci][bro + nn * 1024 + (e0 ^ 32)];
        }
    };

    // ---- prologue: tile0 all 4 chunks + tile1 {A0,B1}; confirm tile0, keep 4 in flight
    stage(0, 0, 0, 0); stage(2, 1, 0, 0); stage(3, 1, 1, 0); stage(1, 0, 1, 0);
    stage(4, 0, 0, 1); stage(7, 1, 1, 1);
    VM4; SB; BARR; SB;

    // ---- main loop: iters t=0,2,4,6,8 (tiles 0..9), stages target up to tile 11
#pragma unroll 1
    for (int t = 0; t < NT - 2; t += 2) {
        // p0: quad(0,0) tile t (slot0)
        stage(6, 1, 0, t + 1);                   // B0 s1
        rdA(0); rdB(2);
        SB; BARR; LG0; SB;
        MF16(0, 0)
        SB; BARR; SB;
        // p1: quad(0,1)
        stage(5, 0, 1, t + 1);                   // A1 s1
        rdB(3);
        SB; BARR; LG0; SB;
        MF16(0, 1)
        SB; BARR; SB;
        // p2: quad(1,1)
        stage(0, 0, 0, t + 2);                   // A0 s0
        rdA(1);
        SB; BARR; LG0; SB;
        MF16(1, 1)
        SB; BARR; SB;
        // p3: quad(1,0)
        stage(3, 1, 1, t + 2);                   // B1 s0
        rdB(2);
        SB; BARR; LG0; SB;
        MF16(1, 0)
        VM4;
        SB; BARR; SB;
        // p4: quad(0,0) tile t+1 (slot1)
        stage(2, 1, 0, t + 2);                   // B0 s0
        rdA(4); rdB(6);
        SB; BARR; LG0; SB;
        MF16(0, 0)
        SB; BARR; SB;
        // p5: quad(0,1)
        stage(1, 0, 1, t + 2);                   // A1 s0
        rdB(7);
        SB; BARR; LG0; SB;
        MF16(0, 1)
        SB; BARR; SB;
        // p6: quad(1,1)
        stage(4, 0, 0, t + 3);                   // A0 s1
        rdA(5);
        SB; BARR; LG0; SB;
        MF16(1, 1)
        SB; BARR; SB;
        // p7: quad(1,0)
        stage(7, 1, 1, t + 3);                   // B1 s1
        rdB(6);
        SB; BARR; LG0; SB;
        MF16(1, 0)
        VM4;
        SB; BARR; SB;
    }

    // ---- peeled final iter (tiles 10,11): only p0/p1 stage; drain at p3
    {
        const int t = NT - 2;
        // p0
        stage(6, 1, 0, t + 1);
        rdA(0); rdB(2);
        SB; BARR; LG0; SB;
        MF16(0, 0)
        SB; BARR; SB;
        // p1
        stage(5, 0, 1, t + 1);
        rdB(3);
        SB; BARR; LG0; SB;
        MF16(0, 1)
        SB; BARR; SB;
        // p2
        rdA(1);
        SB; BARR; LG0; SB;
        MF16(1, 1)
        SB; BARR; SB;
        // p3
        rdB(2);
        SB; BARR; LG0; SB;
        MF16(1, 0)
        VM0;
        SB; BARR; SB;
        // p4
        rdA(4); rdB(6);
        SB; BARR; LG0; SB;
        MF16(0, 0)
        SB; BARR; SB;
        // p5
        rdB(7);
        SB; BARR; LG0; SB;
        MF16(0, 1)
        SB; BARR; SB;
        // p6
        rdA(5);
        SB; BARR; LG0; SB;
        MF16(1, 1)
        SB; BARR; SB;
        // p7
        rdB(6);
        SB; BARR; LG0; SB;
        MF16(1, 0)
    }

    // ---- epilogue: wave rows {wm*64}∪{128+wm*64}, cols {wn*32}∪{128+wn*32}
    const int rB = mTile * 256 + wm * 64 + fh * 4;
    const int cB = nTile * 256 + wn * 32 + fl;
#pragma unroll
    for (int mq = 0; mq < 2; ++mq)
#pragma unroll
    for (int mm = 0; mm < 4; ++mm)
#pragma unroll
    for (int nq = 0; nq < 2; ++nq)
#pragma unroll
    for (int nn = 0; nn < 2; ++nn) {
        const int c = cB + nq * 128 + nn * 16;
        if (c >= Yv) continue;
        const int r = rB + mq * 128 + mm * 16;
#pragma unroll
        for (int j = 0; j < 4; ++j)
            Cg[(long)(r + j) * Yv + c] = acc[mq * 4 + mm][nq * 2 + nn][j];
    }
}

// ---------------------------------------------------------------------------
// GEMM: C[M][Nc] = A[M][K] * B[Nc][K]^T   (m97-structure, for the small GEMMs)
template<bool STORE_BF16>
__global__ __launch_bounds__(256)
void gemm_bt(const bf16* __restrict__ Ag, const bf16* __restrict__ Bg,
             void* __restrict__ Cg, int M, int Nc, int K, int ldc,
             long sA, long sB, long sC)
{
    __shared__ bf16 As[128 * 32];
    __shared__ bf16 Bs[128 * 32];

    const int bz = blockIdx.z;
    const bf16* A  = Ag + (long)bz * sA;
    const bf16* Bm = Bg + (long)bz * sB;

    const int bid = blockIdx.x;
    const int nTilesM = M >> 7;
    const int mTile = bid % nTilesM;
    const int nTile = bid / nTilesM;

    const int tid  = threadIdx.x;
    const int wave = tid >> 6;
    const int lane = tid & 63;

    const int sRow = (wave << 4) + (lane >> 2);
    const int sCol = (lane & 3) << 3;

    const long aBase = (long)(mTile * 128) * K;
    const long bBase = (long)(nTile * 128) * K;

    const int fl = lane & 15;
    const int fh = lane >> 4;
    const int wRow = (wave >> 1) << 6;
    const int wCol = (wave & 1) << 6;

    f32x4 acc[4][4] = {};

    for (int k0 = 0; k0 < K; k0 += 32) {
#pragma unroll
        for (int t = 0; t < 2; ++t) {
            const bf16* gA = A  + aBase + (long)(t * 64 + sRow) * K + (k0 + sCol);
            const bf16* gB = Bm + bBase + (long)(t * 64 + sRow) * K + (k0 + sCol);
            bf16* lA = &As[(t * 64 + (wave << 4)) * 32];
            bf16* lB = &Bs[(t * 64 + (wave << 4)) * 32];
            __builtin_amdgcn_global_load_lds(
                (const AS1 void*)gA, (AS3 void*)lA, 16, 0, 0);
            __builtin_amdgcn_global_load_lds(
                (const AS1 void*)gB, (AS3 void*)lB, 16, 0, 0);
        }
        __syncthreads();

        bf16x8 af[4], bfg[4];
#pragma unroll
        for (int m = 0; m < 4; ++m)
            af[m] = *(const bf16x8*)&As[(wRow + m * 16 + fl) * 32 + fh * 8];
#pragma unroll
        for (int n = 0; n < 4; ++n)
            bfg[n] = *(const bf16x8*)&Bs[(wCol + n * 16 + fl) * 32 + fh * 8];
#pragma unroll
        for (int m = 0; m < 4; ++m)
#pragma unroll
            for (int n = 0; n < 4; ++n)
                acc[m][n] = __builtin_amdgcn_mfma_f32_16x16x32_bf16(
                    af[m], bfg[n], acc[m][n], 0, 0, 0);
        __syncthreads();
    }

    const int rBase = mTile * 128 + wRow + fh * 4;
    const int cBase = nTile * 128 + wCol + fl;
#pragma unroll
    for (int m = 0; m < 4; ++m) {
#pragma unroll
        for (int n = 0; n < 4; ++n) {
            int gc = cBase + n * 16;
            int gr = rBase + m * 16;
            if (STORE_BF16) {
                bf16* C = (bf16*)Cg + (long)bz * sC;
#pragma unroll
                for (int j = 0; j < 4; ++j)
                    C[(long)(gr + j) * ldc + gc] = __float2bfloat16(acc[m][n][j]);
            } else {
                float* C = (float*)Cg + (long)bz * sC;
#pragma unroll
                for (int j = 0; j < 4; ++j)
                    C[(long)(gr + j) * ldc + gc] = acc[m][n][j];
            }
        }
    }
}

// ---------------------------------------------------------------------------
// E_y f32 [30000][768] -> bf16 [30208][768], rows >= 30000 zero-filled
__global__ __launch_bounds__(192) void k_cvt_ey(const float* __restrict__ Ey,
                                                bf16* __restrict__ Eyb)
{
    int row = blockIdx.x;
    int d = threadIdx.x * 4;
    union { bf16 h[4]; uint2 u; } pk;
    if (row < Yv) {
        float4 v = *(const float4*)(Ey + (long)row * Dm + d);
        pk.h[0] = __float2bfloat16(v.x); pk.h[1] = __float2bfloat16(v.y);
        pk.h[2] = __float2bfloat16(v.z); pk.h[3] = __float2bfloat16(v.w);
    } else {
        pk.h[0] = pk.h[1] = pk.h[2] = pk.h[3] = __float2bfloat16(0.f);
    }
    *(uint2*)(Eyb + (long)row * Dm + d) = pk.u;
}

// W f32 [768][768] -> WT bf16 with WT[n][k] = W[k][n]; z selects (W_A, W_O)
__global__ void k_wT(const float* __restrict__ WA, const float* __restrict__ WO,
                     bf16* __restrict__ WAT, bf16* __restrict__ WOT)
{
    __shared__ float t[32][33];
    const float* W = blockIdx.z ? WO : WA;
    bf16* WT = blockIdx.z ? WOT : WAT;
    int bx = blockIdx.x * 32;
    int by = blockIdx.y * 32;
    int tx = threadIdx.x, ty = threadIdx.y;
#pragma unroll
    for (int i = 0; i < 32; i += 8)
        t[ty + i][tx] = W[(long)(bx + ty + i) * Dm + (by + tx)];
    __syncthreads();
#pragma unroll
    for (int i = 0; i < 32; i += 8)
        WT[(long)(by + ty + i) * Dm + (bx + tx)] = __float2bfloat16(t[tx][ty + i]);
}

// X = E_v[M_s] -> bf16 [4096][768]
__global__ __launch_bounds__(192) void k_gather(const int* __restrict__ Ms,
                                                const float* __restrict__ Ev,
                                                bf16* __restrict__ Xb)
{
    int token = blockIdx.x;
    int id = Ms[token];
    int d = threadIdx.x * 4;
    float4 v = *(const float4*)(Ev + (long)id * Dm + d);
    union { bf16 h[4]; uint2 u; } pk;
    pk.h[0] = __float2bfloat16(v.x); pk.h[1] = __float2bfloat16(v.y);
    pk.h[2] = __float2bfloat16(v.z); pk.h[3] = __float2bfloat16(v.w);
    *(uint2*)(Xb + (long)token * Dm + d) = pk.u;
}

// XWo bf16 [B][512][768] -> [B][768][512]
__global__ void k_xwoT(const bf16* __restrict__ Xo, bf16* __restrict__ XoT)
{
    __shared__ bf16 t[32][33];
    int b = blockIdx.z;
    const bf16* src = Xo + (long)b * Nseq * Dm;
    bf16* dst = XoT + (long)b * Dm * Nseq;
    int bx = blockIdx.x * 32;
    int by = blockIdx.y * 32;
    int tx = threadIdx.x, ty = threadIdx.y;
#pragma unroll
    for (int i = 0; i < 32; i += 8)
        t[ty + i][tx] = src[(long)(bx + ty + i) * Dm + (by + tx)];
    __syncthreads();
#pragma unroll
    for (int i = 0; i < 32; i += 8)
        dst[(long)(by + ty + i) * Nseq + (bx + tx)] = t[tx][ty + i];
}

// ---------------------------------------------------------------------------
DEV float waveMax(float v) {
#pragma unroll
    for (int o = 32; o > 0; o >>= 1) v = fmaxf(v, __shfl_xor(v, o, 64));
    return v;
}
DEV float waveSum(float v) {
#pragma unroll
    for (int o = 32; o > 0; o >>= 1) v += __shfl_xor(v, o, 64);
    return v;
}

// softmax over j of (L[b,i,j] + (j-i)) with mask; writes A f32 (d_out) + bf16
__global__ __launch_bounds__(256) void k_softmax(const float* __restrict__ L,
                                                 const int* __restrict__ Ms,
                                                 float* __restrict__ Aout,
                                                 bf16* __restrict__ Ab)
{
    __shared__ float red[8];
    int row = blockIdx.x;
    int b = row >> 9, i = row & 511;
    const float* l = L + (long)row * Nseq;
    const int* ms = Ms + (b << 9);
    int t = threadIdx.x;
    int wid = t >> 6, lane = t & 63;
    int j0 = t, j1 = t + 256;

    float a0 = l[j0] + (float)(j0 - i);
    float a1 = l[j1] + (float)(j1 - i);
    if (ms[j0] == 0) a0 = -1e12f;
    if (ms[j1] == 0) a1 = -1e12f;

    float m = waveMax(fmaxf(a0, a1));
    if (lane == 0) red[wid] = m;
    __syncthreads();
    m = fmaxf(fmaxf(red[0], red[1]), fmaxf(red[2], red[3]));

    float e0 = expf(a0 - m), e1 = expf(a1 - m);
    float s = waveSum(e0 + e1);
    if (lane == 0) red[4 + wid] = s;
    __syncthreads();
    s = red[4] + red[5] + red[6] + red[7];
    float inv = 1.0f / s;

    float r0 = e0 * inv, r1 = e1 * inv;
    Aout[(long)row * Nseq + j0] = r0;
    Aout[(long)row * Nseq + j1] = r1;
    Ab[(long)row * Nseq + j0] = __float2bfloat16(r0);
    Ab[(long)row * Nseq + j1] = __float2bfloat16(r1);
}

// H = LN(Qc + E_v[Ms]) * gamma + beta  -> bf16
__global__ __launch_bounds__(256) void k_ln(const float* __restrict__ Qc,
                                            const int* __restrict__ Ms,
                                            const float* __restrict__ Ev,
                                            const float* __restrict__ gamma,
                                            const float* __restrict__ beta,
                                            bf16* __restrict__ Hb)
{
    __shared__ float red[8];
    int row = blockIdx.x;
    int id = Ms[row];
    const float* q = Qc + (long)row * Dm;
    const float* e = Ev + (long)id * Dm;
    int t = threadIdx.x;
    int wid = t >> 6, lane = t & 63;

    float x[3];
#pragma unroll
    for (int c = 0; c < 3; ++c) x[c] = q[t + c * 256] + e[t + c * 256];

    float s = waveSum(x[0] + x[1] + x[2]);
    if (lane == 0) red[wid] = s;
    __syncthreads();
    float mu = (red[0] + red[1] + red[2] + red[3]) * (1.0f / 768.0f);

    float vs = 0.f;
#pragma unroll
    for (int c = 0; c < 3; ++c) { float d = x[c] - mu; vs += d * d; }
    vs = waveSum(vs);
    if (lane == 0) red[4 + wid] = vs;
    __syncthreads();
    float var = (red[4] + red[5] + red[6] + red[7]) * (1.0f / 768.0f);
    float rstd = rsqrtf(var + 1e-5f);

#pragma unroll
    for (int c = 0; c < 3; ++c) {
        int d = t + c * 256;
        Hb[(long)row * Dm + d] =
            __float2bfloat16((x[c] - mu) * rstd * gamma[d] + beta[d]);
    }
}

// ---------------------------------------------------------------------------
extern "C" void kernel_launch(void* const* d_in, const int* in_sizes, int n_in,
                              void* d_out, int out_size, void* d_ws, size_t ws_size,
                              hipStream_t stream)
{
    const int*   Ms    = (const int*)d_in[0];
    const float* Ev    = (const float*)d_in[1];
    const float* Ey    = (const float*)d_in[2];
    const float* WA    = (const float*)d_in[3];
    const float* WO    = (const float*)d_in[4];
    const float* gamma = (const float*)d_in[5];
    const float* beta  = (const float*)d_in[6];

    float* y_out = (float*)d_out;                       // [4096][30000]
    float* A_out = y_out + (size_t)Tok * Yv;            // [8][512][512]

    char* ws = (char*)d_ws;
    size_t off = 0;
    auto alloc = [&](size_t n) { char* p = ws + off; off += (n + 255) & ~(size_t)255; return p; };
    bf16*  Xb    = (bf16*) alloc((size_t)Tok * Dm * 2);
    bf16*  WAbT  = (bf16*) alloc((size_t)Dm * Dm * 2);
    bf16*  WObT  = (bf16*) alloc((size_t)Dm * Dm * 2);
    bf16*  QWb   = (bf16*) alloc((size_t)Tok * Dm * 2);
    bf16*  XWob  = (bf16*) alloc((size_t)Tok * Dm * 2);
    bf16*  XWobT = (bf16*) alloc((size_t)Tok * Dm * 2);
    float* Lf    = (float*)alloc((size_t)Tok * Nseq * 4);
    bf16*  Ab    = (bf16*) alloc((size_t)Tok * Nseq * 2);
    float* Qc    = (float*)alloc((size_t)Tok * Dm * 4);
    bf16*  Hb    = (bf16*) alloc((size_t)Tok * Dm * 2);
    bf16*  Eyb   = (bf16*) alloc((size_t)Ypad * Dm * 2);

    // 1. convert + pad E_y
    k_cvt_ey<<<dim3(Ypad), dim3(192), 0, stream>>>(Ey, Eyb);
    // 2. transpose-convert W_A and W_O (one launch)
    k_wT<<<dim3(24, 24, 2), dim3(32, 8), 0, stream>>>(WA, WO, WAbT, WObT);
    // 3. gather embeddings
    k_gather<<<dim3(Tok), dim3(192), 0, stream>>>(Ms, Ev, Xb);
    // 4. QW = X @ W_A  (bf16 out)
    gemm_bt<true><<<dim3(192), dim3(256), 0, stream>>>(
        Xb, WAbT, (void*)QWb, Tok, Dm, Dm, Dm, 0L, 0L, 0L);
    // 5. XWo = X @ W_O (bf16 out)
    gemm_bt<true><<<dim3(192), dim3(256), 0, stream>>>(
        Xb, WObT, (void*)XWob, Tok, Dm, Dm, Dm, 0L, 0L, 0L);
    // 6. logits = QW @ X^T per batch (f32 out)
    gemm_bt<false><<<dim3(16, 1, 8), dim3(256), 0, stream>>>(
        QWb, Xb, (void*)Lf, Nseq, Nseq, Dm, Nseq,
        (long)Nseq * Dm, (long)Nseq * Dm, (long)Nseq * Nseq);
    // 7. bias + mask + softmax -> A (f32 in d_out) and Ab (bf16)
    k_softmax<<<dim3(Tok), dim3(256), 0, stream>>>(Lf, Ms, A_out, Ab);
    // 8. transpose XWo per batch
    k_xwoT<<<dim3(16, 24, 8), dim3(32, 8), 0, stream>>>(XWob, XWobT);
    // 9. Qc = A @ XWo per batch (f32 out)
    gemm_bt<false><<<dim3(24, 1, 8), dim3(256), 0, stream>>>(
        Ab, XWobT, (void*)Qc, Nseq, Dm, Nseq, Dm,
        (long)Nseq * Nseq, (long)Dm * Nseq, (long)Nseq * Dm);
    // 10. H = LN(Qc + X)
    k_ln<<<dim3(Tok), dim3(256), 0, stream>>>(Qc, Ms, Ev, gamma, beta, Hb);
    // 11. y_logits = H @ E_y^T  (f32, 256^2 8-phase kernel)
    gemm_big<<<dim3(16 * (Ypad / 256)), dim3(512), 0, stream>>>(Hb, Eyb, y_out);
}